// Round 9
// baseline (816.311 us; speedup 1.0000x reference)
//
#include <hip/hip_runtime.h>

#define FEAT 128
#define BIN_NODES 256   // nodes per bin (passB LDS = 256*128*4 = 128 KB)
#define MAXBINS   256   // supports n <= 65536

typedef short bf16x8 __attribute__((ext_vector_type(8)));
typedef float f32x4  __attribute__((ext_vector_type(4)));

__device__ __forceinline__ unsigned pack_bf16x2(float x, float y) {
    unsigned ux = __float_as_uint(x);
    ux = (ux + 0x7fffu + ((ux >> 16) & 1u)) >> 16;          // RNE, low half
    unsigned uy = __float_as_uint(y);
    uy = (uy + 0x7fffu + ((uy >> 16) & 1u)) & 0xffff0000u;  // RNE, high half
    return uy | ux;
}

__device__ __forceinline__ bf16x8 pack8(float4 a, float4 b) {
    uint4 u = make_uint4(pack_bf16x2(a.x, a.y), pack_bf16x2(a.z, a.w),
                         pack_bf16x2(b.x, b.y), pack_bf16x2(b.z, b.w));
    return __builtin_bit_cast(bf16x8, u);
}

// ---------------- K1: fused [gemm -> out + hb] + [passA: edge binning] ----------------
// gemm blocks [0, gemm_blocks): as R8 (verified): wave = 32 rows x 64 cols, 2 row-groups
// x 2 col-halves per block; col-half-0 waves store packed bf16 rows to hb.
// passA blocks: 1024 edges/block. LDS-rank by bin (=dst>>8) with LDS atomics, ONE global
// with-return atomic per distinct (block,bin) to reserve a run in the bin's fixed segment
// (97k atomics total vs R8's 640k -- the 14 G/s with-return atomic path was the R8 wall).
// Edge stored packed (dst<<16)|src; both < 65536.
__global__ __launch_bounds__(256) void fused_kernel(
    const float* __restrict__ h, const float* __restrict__ W,
    const float* __restrict__ b, const int* __restrict__ src,
    const int* __restrict__ dst, float* __restrict__ out,
    uint4* __restrict__ hb4, int* __restrict__ cursor, unsigned* __restrict__ edge_out,
    int nrows, int gemm_blocks, int E, int nbins, int bincap)
{
    const int bid = blockIdx.x;
    const int tid = threadIdx.x;

    if (bid >= gemm_blocks) {
        // ---- passA: bin 1024 edges ----
        __shared__ int cnt[MAXBINS];
        __shared__ int gbase[MAXBINS];
        for (int i = tid; i < nbins; i += 256) cnt[i] = 0;
        __syncthreads();

        int base = (bid - gemm_blocks) * 1024 + tid;
        int dk[4], sk[4], bk[4], lr[4];
#pragma unroll
        for (int k = 0; k < 4; ++k) {
            int e = base + k * 256;
            if (e < E) { dk[k] = dst[e]; sk[k] = src[e]; }
        }
#pragma unroll
        for (int k = 0; k < 4; ++k) {
            int e = base + k * 256;
            if (e < E) {
                bk[k] = dk[k] >> 8;
                lr[k] = atomicAdd(&cnt[bk[k]], 1);
            }
        }
        __syncthreads();
        for (int i = tid; i < nbins; i += 256) {
            int c = cnt[i];
            gbase[i] = (c > 0) ? atomicAdd(&cursor[i], c) : 0;
        }
        __syncthreads();
#pragma unroll
        for (int k = 0; k < 4; ++k) {
            int e = base + k * 256;
            if (e < E) {
                int slot = gbase[bk[k]] + lr[k];
                if (slot < bincap)
                    edge_out[(size_t)bk[k] * bincap + slot] =
                        ((unsigned)dk[k] << 16) | (unsigned)sk[k];
            }
        }
        return;
    }

    // ---- gemm: wave = rows [r0g, r0g+32) x cols [ch*64, ch*64+64) (R8, verified) ----
    const int w    = tid >> 6;
    const int lane = tid & 63;
    const int m    = lane & 15, quad = lane >> 4;
    const int r0g  = bid * 64 + (w >> 1) * 32;
    const int ch   = w & 1;
    if (r0g >= nrows) return;

    const float4* __restrict__ h4 = (const float4*)h;
    const float4* __restrict__ W4 = (const float4*)W;

    bf16x8 af[2][4];
#pragma unroll
    for (int mt = 0; mt < 2; ++mt) {
        int gr = r0g + mt * 16 + m;
#pragma unroll
        for (int ks = 0; ks < 4; ++ks) {
            float4 a0 = h4[(size_t)gr * 32 + ks * 8 + quad * 2];
            float4 a1 = h4[(size_t)gr * 32 + ks * 8 + quad * 2 + 1];
            af[mt][ks] = pack8(a0, a1);
        }
    }

    if (ch == 0) {
#pragma unroll
        for (int mt = 0; mt < 2; ++mt) {
            int gr = r0g + mt * 16 + m;
            if (gr < nrows) {
#pragma unroll
                for (int ks = 0; ks < 4; ++ks)
                    hb4[(size_t)gr * 16 + ks * 4 + quad] = __builtin_bit_cast(uint4, af[mt][ks]);
            }
        }
    }

    f32x4 acc[2][4];
#pragma unroll
    for (int mt = 0; mt < 2; ++mt)
#pragma unroll
        for (int n = 0; n < 4; ++n) acc[mt][n] = (f32x4){0.f, 0.f, 0.f, 0.f};

#pragma unroll
    for (int n = 0; n < 4; ++n) {
        int c = (ch * 4 + n) * 16 + m;
#pragma unroll
        for (int ks = 0; ks < 4; ++ks) {
            float4 b0 = W4[(size_t)c * 32 + ks * 8 + quad * 2];
            float4 b1 = W4[(size_t)c * 32 + ks * 8 + quad * 2 + 1];
            bf16x8 bf = pack8(b0, b1);
#pragma unroll
            for (int mt = 0; mt < 2; ++mt)
                acc[mt][n] = __builtin_amdgcn_mfma_f32_16x16x32_bf16(
                    af[mt][ks], bf, acc[mt][n], 0, 0, 0);
        }
    }

#pragma unroll
    for (int n = 0; n < 4; ++n) {
        int col = (ch * 4 + n) * 16 + m;
        float bias = b[col];
#pragma unroll
        for (int mt = 0; mt < 2; ++mt)
#pragma unroll
            for (int r = 0; r < 4; ++r) {
                int gr = r0g + mt * 16 + quad * 4 + r;
                if (gr < nrows)
                    __builtin_nontemporal_store(acc[mt][n][r] + bias,
                                                &out[(size_t)gr * FEAT + col]);
            }
    }
}

// ---------------- K2 (passB): per-bin LDS-privatized scatter-add ----------------
// Block g owns nodes [g*256, g*256+256): 128 KB LDS f32 accumulator. Reads its bin's
// contiguous edge run (coalesced), shfl-broadcasts each packed edge (wave-uniform
// bounds -> full exec mask, R5 invariant), accumulates h rows via ds_add_f32
// (lane covers feats 2l,2l+1: 2-way bank aliasing = free). Coalesced agg writeout.
__global__ __launch_bounds__(1024) void passB_kernel(
    const unsigned* __restrict__ hb, const int* __restrict__ cursor,
    const unsigned* __restrict__ edge_out, float* __restrict__ agg,
    int N, int bincap)
{
    __shared__ float aggl[BIN_NODES * FEAT];   // 128 KB

    const int g    = blockIdx.x;
    const int tid  = threadIdx.x;
    const int wid  = tid >> 6;
    const int lane = tid & 63;

    {
        f32x4* az = (f32x4*)aggl;
#pragma unroll
        for (int i = 0; i < 8; ++i) az[tid + i * 1024] = (f32x4){0.f, 0.f, 0.f, 0.f};
    }
    __syncthreads();

    int cnt = cursor[g];
    cnt = (cnt > bincap) ? bincap : cnt;
    const unsigned* run = edge_out + (size_t)g * bincap;
    const unsigned nbase = (unsigned)(g << 8);

    // 16 waves stride over 64-edge chunks
    for (int c0 = wid * 64; c0 < cnt; c0 += 16 * 64) {
        int idx = c0 + lane;
        unsigned pk = (idx < cnt) ? run[idx] : 0u;   // load predicated; shfl below full-exec
        int mlim = cnt - c0; mlim = (mlim > 64) ? 64 : mlim;
        int t = 0;
        for (; t + 2 <= mlim; t += 2) {
            unsigned e0 = __shfl(pk, t);
            unsigned e1 = __shfl(pk, t + 1);
            unsigned v0 = hb[(size_t)(e0 & 0xffffu) * 64 + lane];
            unsigned v1 = hb[(size_t)(e1 & 0xffffu) * 64 + lane];
            int a0 = (int)((e0 >> 16) - nbase) * FEAT + 2 * lane;
            int a1 = (int)((e1 >> 16) - nbase) * FEAT + 2 * lane;
            atomicAdd(&aggl[a0],     __uint_as_float(v0 << 16));
            atomicAdd(&aggl[a0 + 1], __uint_as_float(v0 & 0xffff0000u));
            atomicAdd(&aggl[a1],     __uint_as_float(v1 << 16));
            atomicAdd(&aggl[a1 + 1], __uint_as_float(v1 & 0xffff0000u));
        }
        {   // tail (mlim odd): shfl full-exec, accumulate predicated
            unsigned e0 = __shfl(pk, t & 63);
            if (t < mlim) {
                unsigned v0 = hb[(size_t)(e0 & 0xffffu) * 64 + lane];
                int a0 = (int)((e0 >> 16) - nbase) * FEAT + 2 * lane;
                atomicAdd(&aggl[a0],     __uint_as_float(v0 << 16));
                atomicAdd(&aggl[a0 + 1], __uint_as_float(v0 & 0xffff0000u));
            }
        }
    }
    __syncthreads();

    // writeout: valid nodes * 32 f32x4 units, thread-strided (coalesced)
    int valid = N - (g << 8);
    valid = (valid > BIN_NODES) ? BIN_NODES : valid;
    int units = valid * (FEAT / 4);
    f32x4* aggv = (f32x4*)agg + (size_t)(g << 8) * (FEAT / 4);
    f32x4* al   = (f32x4*)aggl;
    for (int u = tid; u < units; u += 1024)
        __builtin_nontemporal_store(al[u], &aggv[u]);
}

// ---------------- fallback path (ws too small): f32 vector GEMM + atomic scatter ----------------
__global__ __launch_bounds__(256, 2) void gemm_f32_kernel(
    const float* __restrict__ h, const float* __restrict__ W,
    const float* __restrict__ b, float* __restrict__ out, int nrows)
{
    __shared__ float4 wsh[128 * 8];
    __shared__ float4 hsh[64 * 8];
    const int tid = threadIdx.x;
    const int tx  = tid & 31;
    const int ty  = tid >> 5;
    const int r0  = blockIdx.x * 64;
    const float4* __restrict__ W4 = (const float4*)W;
    const float4* __restrict__ h4 = (const float4*)h;
    float acc[8][4];
#pragma unroll
    for (int i = 0; i < 8; ++i)
#pragma unroll
        for (int j = 0; j < 4; ++j) acc[i][j] = 0.f;
    for (int p = 0; p < 4; ++p) {
        if (p) __syncthreads();
#pragma unroll
        for (int l = 0; l < 4; ++l) {
            int flat = l * 256 + tid;
            int c = flat >> 3, kc = flat & 7;
            wsh[c * 8 + (kc ^ ((c >> 2) & 7))] = W4[c * 32 + p * 8 + kc];
        }
#pragma unroll
        for (int l = 0; l < 2; ++l) {
            int flat = l * 256 + tid;
            int r = flat >> 3, kc = flat & 7;
            int gr = r0 + r;
            float4 v = make_float4(0.f, 0.f, 0.f, 0.f);
            if (gr < nrows) v = h4[(size_t)gr * 32 + p * 8 + kc];
            hsh[r * 8 + (kc ^ ((r >> 2) & 7))] = v;
        }
        __syncthreads();
#pragma unroll
        for (int kc = 0; kc < 8; ++kc) {
            float4 wv[4], hv[8];
#pragma unroll
            for (int j = 0; j < 4; ++j) wv[j] = wsh[(4 * tx + j) * 8 + (kc ^ (tx & 7))];
#pragma unroll
            for (int i = 0; i < 8; ++i) {
                int r = 8 * ty + i;
                hv[i] = hsh[r * 8 + (kc ^ ((r >> 2) & 7))];
            }
#pragma unroll
            for (int i = 0; i < 8; ++i)
#pragma unroll
                for (int j = 0; j < 4; ++j) {
                    acc[i][j] += hv[i].x * wv[j].x;
                    acc[i][j] += hv[i].y * wv[j].y;
                    acc[i][j] += hv[i].z * wv[j].z;
                    acc[i][j] += hv[i].w * wv[j].w;
                }
        }
    }
    const float4 bj = ((const float4*)b)[tx];
    float4* out4 = (float4*)out;
#pragma unroll
    for (int i = 0; i < 8; ++i) {
        int gr = r0 + 8 * ty + i;
        if (gr < nrows) {
            float4 o;
            o.x = acc[i][0] + bj.x; o.y = acc[i][1] + bj.y;
            o.z = acc[i][2] + bj.z; o.w = acc[i][3] + bj.w;
            out4[(size_t)gr * 32 + tx] = o;
        }
    }
}

__global__ __launch_bounds__(256) void scatter_add_kernel(
    const float* __restrict__ h, const int* __restrict__ src,
    const int* __restrict__ dst, float* __restrict__ agg, int E)
{
    int gid  = blockIdx.x * 256 + threadIdx.x;
    int e    = gid >> 6;
    int lane = gid & 63;
    if (e >= E) return;
    int s = src[e];
    int d = dst[e];
    const float2* hp = (const float2*)(h + (size_t)s * FEAT);
    float2 v = hp[lane];
    float* ap = agg + (size_t)d * FEAT + 2 * lane;
    unsafeAtomicAdd(ap,     v.x);
    unsafeAtomicAdd(ap + 1, v.y);
}

extern "C" void kernel_launch(void* const* d_in, const int* in_sizes, int n_in,
                              void* d_out, int out_size, void* d_ws, size_t ws_size,
                              hipStream_t stream) {
    const float* h   = (const float*)d_in[0];
    const float* W   = (const float*)d_in[1];
    const float* b   = (const float*)d_in[2];
    const int*   src = (const int*)d_in[3];
    const int*   dst = (const int*)d_in[4];

    const int n = in_sizes[0] / FEAT;   // 40000 nodes
    const int E = in_sizes[3];          // 640000 edges

    float* out = (float*)d_out;
    float* agg = out + (size_t)n * FEAT;

    const int nbins = (n + BIN_NODES - 1) / BIN_NODES;   // 157
    // bincap = mean + 8*sigma + margin (Binomial tail ~1e-15)
    int mean = (E + nbins - 1) / nbins;
    int bincap = mean + 8 * (int)(__builtin_sqrt((double)mean) + 1) + 64;

    // ws layout: [hb: n*256 B][edge_out: nbins*bincap uints][cursor: nbins ints]
    size_t hb_bytes = (size_t)n * FEAT * 2;
    size_t eo_bytes = (size_t)nbins * bincap * 4;
    size_t cu_bytes = (size_t)nbins * 4;
    size_t need = hb_bytes + eo_bytes + cu_bytes;

    if (ws_size >= need && n <= 65535 && nbins <= MAXBINS) {
        uint4*    hb       = (uint4*)d_ws;
        unsigned* edge_out = (unsigned*)((char*)d_ws + hb_bytes);
        int*      cursor   = (int*)((char*)d_ws + hb_bytes + eo_bytes);

        (void)hipMemsetAsync(cursor, 0, cu_bytes, stream);

        int gemm_blocks  = (n + 63) / 64;
        int passA_blocks = (E + 1023) / 1024;
        fused_kernel<<<dim3(gemm_blocks + passA_blocks), dim3(256), 0, stream>>>(
            h, W, b, src, dst, out, hb, cursor, edge_out, n, gemm_blocks, E, nbins, bincap);

        passB_kernel<<<dim3(nbins), dim3(1024), 0, stream>>>(
            (const unsigned*)hb, cursor, edge_out, agg, n, bincap);
    } else {
        gemm_f32_kernel<<<dim3((n + 63) / 64), dim3(256), 0, stream>>>(h, W, b, out, n);
        (void)hipMemsetAsync(agg, 0, (size_t)n * FEAT * sizeof(float), stream);
        int nblocks = (int)(((long long)E * 64 + 255) / 256);
        scatter_add_kernel<<<dim3(nblocks), dim3(256), 0, stream>>>(h, src, dst, agg, E);
    }
}

// Round 10
// 147.138 us; speedup vs baseline: 5.5479x; 5.5479x over previous
//
#include <hip/hip_runtime.h>

#define FEAT 128
#define CAP  64        // bucket capacity per node; Poisson(16), P(deg>64)~1e-20
#define BIN_NODES 256  // nodes per bin; all edges of a node land in one bin
#define MAXBINS   256  // supports n <= 65536 (also required by (dst<<16)|src packing)

typedef short bf16x8 __attribute__((ext_vector_type(8)));
typedef float f32x4  __attribute__((ext_vector_type(4)));

__device__ __forceinline__ unsigned pack_bf16x2(float x, float y) {
    unsigned ux = __float_as_uint(x);
    ux = (ux + 0x7fffu + ((ux >> 16) & 1u)) >> 16;          // RNE, low half
    unsigned uy = __float_as_uint(y);
    uy = (uy + 0x7fffu + ((uy >> 16) & 1u)) & 0xffff0000u;  // RNE, high half
    return uy | ux;
}

__device__ __forceinline__ bf16x8 pack8(float4 a, float4 b) {
    uint4 u = make_uint4(pack_bf16x2(a.x, a.y), pack_bf16x2(a.z, a.w),
                         pack_bf16x2(b.x, b.y), pack_bf16x2(b.z, b.w));
    return __builtin_bit_cast(bf16x8, u);
}

__device__ __forceinline__ f32x4 unpack2(unsigned x, unsigned y) {
    return (f32x4){__uint_as_float(x << 16), __uint_as_float(x & 0xffff0000u),
                   __uint_as_float(y << 16), __uint_as_float(y & 0xffff0000u)};
}

// ---------------- K1: fused [gemm -> out + hb] + [passA: edge binning] ----------------
// gemm (R8-verified): wave = 32 rows x 64 cols; col-half-0 waves store packed bf16 rows to hb.
// passA (R9-verified): 1024 edges/block, LDS-rank by bin (=dst>>8), ONE global with-return
// atomic per distinct (block,bin) (~98k total vs R8's 640k -- with-return atomics run
// ~16 G/s, the R8 fill wall). Edges stored packed (dst<<16)|src in bin segments.
__global__ __launch_bounds__(256) void fused_kernel(
    const float* __restrict__ h, const float* __restrict__ W,
    const float* __restrict__ b, const int* __restrict__ src,
    const int* __restrict__ dst, float* __restrict__ out,
    uint4* __restrict__ hb4, int* __restrict__ cursor, unsigned* __restrict__ edge_out,
    int nrows, int gemm_blocks, int E, int nbins, int bincap)
{
    const int bid = blockIdx.x;
    const int tid = threadIdx.x;

    if (bid >= gemm_blocks) {
        // ---- passA: bin 1024 edges ----
        __shared__ int cnt[MAXBINS];
        __shared__ int gbase[MAXBINS];
        for (int i = tid; i < nbins; i += 256) cnt[i] = 0;
        __syncthreads();

        int base = (bid - gemm_blocks) * 1024 + tid;
        int dk[4], sk[4], bk[4], lr[4];
#pragma unroll
        for (int k = 0; k < 4; ++k) {
            int e = base + k * 256;
            if (e < E) { dk[k] = dst[e]; sk[k] = src[e]; }
        }
#pragma unroll
        for (int k = 0; k < 4; ++k) {
            int e = base + k * 256;
            if (e < E) {
                bk[k] = dk[k] >> 8;
                lr[k] = atomicAdd(&cnt[bk[k]], 1);
            }
        }
        __syncthreads();
        for (int i = tid; i < nbins; i += 256) {
            int c = cnt[i];
            gbase[i] = (c > 0) ? atomicAdd(&cursor[i], c) : 0;
        }
        __syncthreads();
#pragma unroll
        for (int k = 0; k < 4; ++k) {
            int e = base + k * 256;
            if (e < E) {
                int slot = gbase[bk[k]] + lr[k];
                if (slot < bincap)
                    edge_out[(size_t)bk[k] * bincap + slot] =
                        ((unsigned)dk[k] << 16) | (unsigned)sk[k];
            }
        }
        return;
    }

    // ---- gemm: wave = rows [r0g, r0g+32) x cols [ch*64, ch*64+64) (R8, verified) ----
    const int w    = tid >> 6;
    const int lane = tid & 63;
    const int m    = lane & 15, quad = lane >> 4;
    const int r0g  = bid * 64 + (w >> 1) * 32;
    const int ch   = w & 1;
    if (r0g >= nrows) return;

    const float4* __restrict__ h4 = (const float4*)h;
    const float4* __restrict__ W4 = (const float4*)W;

    bf16x8 af[2][4];
#pragma unroll
    for (int mt = 0; mt < 2; ++mt) {
        int gr = r0g + mt * 16 + m;
#pragma unroll
        for (int ks = 0; ks < 4; ++ks) {
            float4 a0 = h4[(size_t)gr * 32 + ks * 8 + quad * 2];
            float4 a1 = h4[(size_t)gr * 32 + ks * 8 + quad * 2 + 1];
            af[mt][ks] = pack8(a0, a1);
        }
    }

    if (ch == 0) {
#pragma unroll
        for (int mt = 0; mt < 2; ++mt) {
            int gr = r0g + mt * 16 + m;
            if (gr < nrows) {
#pragma unroll
                for (int ks = 0; ks < 4; ++ks)
                    hb4[(size_t)gr * 16 + ks * 4 + quad] = __builtin_bit_cast(uint4, af[mt][ks]);
            }
        }
    }

    f32x4 acc[2][4];
#pragma unroll
    for (int mt = 0; mt < 2; ++mt)
#pragma unroll
        for (int n = 0; n < 4; ++n) acc[mt][n] = (f32x4){0.f, 0.f, 0.f, 0.f};

#pragma unroll
    for (int n = 0; n < 4; ++n) {
        int c = (ch * 4 + n) * 16 + m;
#pragma unroll
        for (int ks = 0; ks < 4; ++ks) {
            float4 b0 = W4[(size_t)c * 32 + ks * 8 + quad * 2];
            float4 b1 = W4[(size_t)c * 32 + ks * 8 + quad * 2 + 1];
            bf16x8 bf = pack8(b0, b1);
#pragma unroll
            for (int mt = 0; mt < 2; ++mt)
                acc[mt][n] = __builtin_amdgcn_mfma_f32_16x16x32_bf16(
                    af[mt][ks], bf, acc[mt][n], 0, 0, 0);
        }
    }

#pragma unroll
    for (int n = 0; n < 4; ++n) {
        int col = (ch * 4 + n) * 16 + m;
        float bias = b[col];
#pragma unroll
        for (int mt = 0; mt < 2; ++mt)
#pragma unroll
            for (int r = 0; r < 4; ++r) {
                int gr = r0g + mt * 16 + quad * 4 + r;
                if (gr < nrows)
                    __builtin_nontemporal_store(acc[mt][n][r] + bias,
                                                &out[(size_t)gr * FEAT + col]);
            }
    }
}

// ---------------- K2: rank — per-bin LDS ranking -> global buckets + counts ----------------
// All edges of node d live in bin d>>8, so per-node ranks from LDS atomics (fast path,
// ~16 adds/counter) are globally correct. Scatters src into bucket[node*CAP+rank] and
// writes counts -- exactly the structures R8's verified gather consumes. No global
// with-return atomics here (that was R8's 40 us wall).
__global__ __launch_bounds__(1024) void rank_kernel(
    const int* __restrict__ cursor, const unsigned* __restrict__ edge_out,
    int* __restrict__ bucket, int* __restrict__ counts, int N, int bincap)
{
    __shared__ int cnt[BIN_NODES];
    const int g = blockIdx.x, tid = threadIdx.x;
    if (tid < BIN_NODES) cnt[tid] = 0;
    __syncthreads();

    int c = cursor[g];
    c = (c > bincap) ? bincap : c;
    const unsigned* run = edge_out + (size_t)g * bincap;
    const int nb = g << 8;

    for (int i = tid; i < c; i += 1024) {
        unsigned pk = run[i];
        int ld = (int)(pk >> 16) - nb;          // 0..255 local node
        int r = atomicAdd(&cnt[ld], 1);
        if (r < CAP)
            bucket[(size_t)(nb + ld) * CAP + r] = (int)(pk & 0xffffu);
    }
    __syncthreads();

    if (tid < BIN_NODES) {
        int node = nb + tid;
        if (node < N) counts[node] = cnt[tid];
    }
}

// ---------------- K3: gather (R8-verified) — one wave per node, quarter-wave per edge ----------------
// Register accumulation + 40000-wave oversubscription (R9 lesson: this is what makes it
// fast). INVARIANT: every __shfl under FULL exec mask; only load+accumulate predicated.
__global__ __launch_bounds__(256) void gather_bucket_kernel(
    const uint4* __restrict__ hb4, const int* __restrict__ counts,
    const int* __restrict__ bucket, float* __restrict__ agg, int N)
{
    int gid  = blockIdx.x * 256 + threadIdx.x;
    int node = gid >> 6;
    int lane = gid & 63;
    if (node >= N) return;

    int deg = counts[node];
    deg = (deg > CAP) ? CAP : deg;
    int eid = (lane < deg) ? bucket[node * CAP + lane] : 0;

    const int q = lane >> 4, ql = lane & 15;

    f32x4 al0 = {0.f,0.f,0.f,0.f}, ah0 = {0.f,0.f,0.f,0.f};
    f32x4 al1 = {0.f,0.f,0.f,0.f}, ah1 = {0.f,0.f,0.f,0.f};

    int t = 0;
    for (; t + 8 <= deg; t += 8) {   // uniform condition: all 64 lanes active
        int s0 = __shfl(eid, t + q);
        int s1 = __shfl(eid, t + 4 + q);
        uint4 v0 = hb4[(size_t)s0 * 16 + ql];
        uint4 v1 = hb4[(size_t)s1 * 16 + ql];
        al0 += unpack2(v0.x, v0.y);
        ah0 += unpack2(v0.z, v0.w);
        al1 += unpack2(v1.x, v1.y);
        ah1 += unpack2(v1.z, v1.w);
    }
    {   // tail: shfls wave-uniform (clamped), accumulate predicated
        int i0 = t + q, i1 = t + 4 + q;
        int s0 = __shfl(eid, i0 & 63);
        int s1 = __shfl(eid, i1 & 63);
        if (i0 < deg) {
            uint4 v = hb4[(size_t)s0 * 16 + ql];
            al0 += unpack2(v.x, v.y);
            ah0 += unpack2(v.z, v.w);
        }
        if (i1 < deg) {
            uint4 v = hb4[(size_t)s1 * 16 + ql];
            al1 += unpack2(v.x, v.y);
            ah1 += unpack2(v.z, v.w);
        }
    }
    al0 += al1; ah0 += ah1;

#pragma unroll
    for (int j = 0; j < 4; ++j) {
        al0[j] += __shfl_down(al0[j], 32);
        ah0[j] += __shfl_down(ah0[j], 32);
        al0[j] += __shfl_down(al0[j], 16);
        ah0[j] += __shfl_down(ah0[j], 16);
    }

    if (q == 0) {
        f32x4* aggv = (f32x4*)agg;
        __builtin_nontemporal_store(al0, &aggv[(size_t)node * 32 + ql * 2]);
        __builtin_nontemporal_store(ah0, &aggv[(size_t)node * 32 + ql * 2 + 1]);
    }
}

// ---------------- fallback path (ws too small): f32 vector GEMM + atomic scatter ----------------
__global__ __launch_bounds__(256, 2) void gemm_f32_kernel(
    const float* __restrict__ h, const float* __restrict__ W,
    const float* __restrict__ b, float* __restrict__ out, int nrows)
{
    __shared__ float4 wsh[128 * 8];
    __shared__ float4 hsh[64 * 8];
    const int tid = threadIdx.x;
    const int tx  = tid & 31;
    const int ty  = tid >> 5;
    const int r0  = blockIdx.x * 64;
    const float4* __restrict__ W4 = (const float4*)W;
    const float4* __restrict__ h4 = (const float4*)h;
    float acc[8][4];
#pragma unroll
    for (int i = 0; i < 8; ++i)
#pragma unroll
        for (int j = 0; j < 4; ++j) acc[i][j] = 0.f;
    for (int p = 0; p < 4; ++p) {
        if (p) __syncthreads();
#pragma unroll
        for (int l = 0; l < 4; ++l) {
            int flat = l * 256 + tid;
            int c = flat >> 3, kc = flat & 7;
            wsh[c * 8 + (kc ^ ((c >> 2) & 7))] = W4[c * 32 + p * 8 + kc];
        }
#pragma unroll
        for (int l = 0; l < 2; ++l) {
            int flat = l * 256 + tid;
            int r = flat >> 3, kc = flat & 7;
            int gr = r0 + r;
            float4 v = make_float4(0.f, 0.f, 0.f, 0.f);
            if (gr < nrows) v = h4[(size_t)gr * 32 + p * 8 + kc];
            hsh[r * 8 + (kc ^ ((r >> 2) & 7))] = v;
        }
        __syncthreads();
#pragma unroll
        for (int kc = 0; kc < 8; ++kc) {
            float4 wv[4], hv[8];
#pragma unroll
            for (int j = 0; j < 4; ++j) wv[j] = wsh[(4 * tx + j) * 8 + (kc ^ (tx & 7))];
#pragma unroll
            for (int i = 0; i < 8; ++i) {
                int r = 8 * ty + i;
                hv[i] = hsh[r * 8 + (kc ^ ((r >> 2) & 7))];
            }
#pragma unroll
            for (int i = 0; i < 8; ++i)
#pragma unroll
                for (int j = 0; j < 4; ++j) {
                    acc[i][j] += hv[i].x * wv[j].x;
                    acc[i][j] += hv[i].y * wv[j].y;
                    acc[i][j] += hv[i].z * wv[j].z;
                    acc[i][j] += hv[i].w * wv[j].w;
                }
        }
    }
    const float4 bj = ((const float4*)b)[tx];
    float4* out4 = (float4*)out;
#pragma unroll
    for (int i = 0; i < 8; ++i) {
        int gr = r0 + 8 * ty + i;
        if (gr < nrows) {
            float4 o;
            o.x = acc[i][0] + bj.x; o.y = acc[i][1] + bj.y;
            o.z = acc[i][2] + bj.z; o.w = acc[i][3] + bj.w;
            out4[(size_t)gr * 32 + tx] = o;
        }
    }
}

__global__ __launch_bounds__(256) void scatter_add_kernel(
    const float* __restrict__ h, const int* __restrict__ src,
    const int* __restrict__ dst, float* __restrict__ agg, int E)
{
    int gid  = blockIdx.x * 256 + threadIdx.x;
    int e    = gid >> 6;
    int lane = gid & 63;
    if (e >= E) return;
    int s = src[e];
    int d = dst[e];
    const float2* hp = (const float2*)(h + (size_t)s * FEAT);
    float2 v = hp[lane];
    float* ap = agg + (size_t)d * FEAT + 2 * lane;
    unsafeAtomicAdd(ap,     v.x);
    unsafeAtomicAdd(ap + 1, v.y);
}

extern "C" void kernel_launch(void* const* d_in, const int* in_sizes, int n_in,
                              void* d_out, int out_size, void* d_ws, size_t ws_size,
                              hipStream_t stream) {
    const float* h   = (const float*)d_in[0];
    const float* W   = (const float*)d_in[1];
    const float* b   = (const float*)d_in[2];
    const int*   src = (const int*)d_in[3];
    const int*   dst = (const int*)d_in[4];

    const int n = in_sizes[0] / FEAT;   // 40000 nodes
    const int E = in_sizes[3];          // 640000 edges

    float* out = (float*)d_out;
    float* agg = out + (size_t)n * FEAT;

    const int nbins = (n + BIN_NODES - 1) / BIN_NODES;   // 157
    int mean = (E + nbins - 1) / nbins;
    int bincap = mean + 8 * (int)(__builtin_sqrt((double)mean) + 1) + 64;

    // ws: [hb n*256B][edge_out nbins*bincap u32][bucket n*CAP i32][counts n i32][cursor nbins i32]
    size_t hb_bytes = (size_t)n * FEAT * 2;
    size_t eo_bytes = (size_t)nbins * bincap * 4;
    size_t bu_bytes = (size_t)n * CAP * 4;
    size_t co_bytes = (size_t)n * 4;
    size_t cu_bytes = (size_t)nbins * 4;
    size_t need = hb_bytes + eo_bytes + bu_bytes + co_bytes + cu_bytes;

    if (ws_size >= need && n <= 65535 && nbins <= MAXBINS) {
        char* p = (char*)d_ws;
        uint4*    hb       = (uint4*)p;                 p += hb_bytes;
        unsigned* edge_out = (unsigned*)p;              p += eo_bytes;
        int*      bucket   = (int*)p;                   p += bu_bytes;
        int*      counts   = (int*)p;                   p += co_bytes;
        int*      cursor   = (int*)p;

        (void)hipMemsetAsync(cursor, 0, cu_bytes, stream);

        int gemm_blocks  = (n + 63) / 64;
        int passA_blocks = (E + 1023) / 1024;
        fused_kernel<<<dim3(gemm_blocks + passA_blocks), dim3(256), 0, stream>>>(
            h, W, b, src, dst, out, hb, cursor, edge_out, n, gemm_blocks, E, nbins, bincap);

        rank_kernel<<<dim3(nbins), dim3(1024), 0, stream>>>(
            cursor, edge_out, bucket, counts, n, bincap);

        gather_bucket_kernel<<<dim3((int)(((long long)n * 64 + 255) / 256)), dim3(256), 0, stream>>>(
            hb, counts, bucket, agg, n);
    } else {
        gemm_f32_kernel<<<dim3((n + 63) / 64), dim3(256), 0, stream>>>(h, W, b, out, n);
        (void)hipMemsetAsync(agg, 0, (size_t)n * FEAT * sizeof(float), stream);
        int nblocks = (int)(((long long)E * 64 + 255) / 256);
        scatter_add_kernel<<<dim3(nblocks), dim3(256), 0, stream>>>(h, src, dst, agg, E);
    }
}